// Round 2
// baseline (1184.177 us; speedup 1.0000x reference)
//
#include <hip/hip_runtime.h>
#include <math.h>

#define B_IN   32
#define BATCH  16
#define F_IN   16
#define F_OUT  64
#define NGRID  32
#define NSPEC  256
#define NHALF  2856          // sum (l+1)(2l+1), l<16  (m>=0 half of spec3)
#define SCALING 0.005524271728019903f
#define PI_F 3.14159265358979323846f
#define W32 0.19634954084936207f   // 2*pi/32

// hof2[l] = hoff[l] + l  (packed Fz base, so offset = hof2[l] + m*(2l+1) + n)
__device__ const int d_hof2[16] = {0,2,9,25,54,100,167,259,380,534,725,957,1234,1560,1939,2375};
// cof2[l] = c_off[l] + 2l(l+1)   (wig_so3 base, so offset = cof2[l] + m*(2l+1) + n)
__device__ const int d_cof2[16] = {0,5,22,59,124,225,370,567,824,1149,1550,2035,2612,3289,4074,4975};
// hoff[l] (packed half-Fz block starts)
__device__ const int d_hof[16]  = {0,1,7,22,50,95,161,252,372,525,715,946,1222,1547,1925,2360};

// ---------------- K1: fhat[s][b][f] for m>=0 only (136 s values) ----------------
__global__ __launch_bounds__(256) void k1_fhat(const float* __restrict__ x,
                                               const float* __restrict__ wig_s2,
                                               float2* __restrict__ fhat) {
    __shared__ float  xs[64][65];     // padded: bank = (j + a) & 31
    __shared__ float2 xf[16][65];     // [m][j]
    const int b = blockIdx.x >> 4, f = blockIdx.x & 15;
    const int tid = threadIdx.x;

    const float4* src = (const float4*)(x + (size_t)(b * F_IN + f) * 4096);
    for (int t = tid; t < 1024; t += 256) {
        float4 v = src[t];
        const int row = t >> 4, col = (t & 15) * 4;
        xs[row][col] = v.x; xs[row][col+1] = v.y; xs[row][col+2] = v.z; xs[row][col+3] = v.w;
    }
    __syncthreads();

    // alpha DFT, m = tid>>4 (0..15), j = (tid&15) + 16*q
    {
        const int m = tid >> 4, j0 = tid & 15;
        float stc, sts;
        sincosf(-(2.f * PI_F / 64.f) * (float)m, &sts, &stc);
        float wr = 1.f, wi = 0.f;
        float ar[4] = {0,0,0,0}, ai[4] = {0,0,0,0};
        #pragma unroll 8
        for (int a = 0; a < 64; ++a) {
            #pragma unroll
            for (int q = 0; q < 4; ++q) {
                const float v = xs[j0 + 16*q][a];
                ar[q] += v * wr; ai[q] += v * wi;
            }
            const float nr = wr*stc - wi*sts; wi = wr*sts + wi*stc; wr = nr;
        }
        #pragma unroll
        for (int q = 0; q < 4; ++q) xf[m][j0 + 16*q] = make_float2(ar[q], ai[q]);
    }
    __syncthreads();

    // beta contraction: u = tid in [0,136): triangular (l,m)
    if (tid < 136) {
        int l = (int)((sqrtf(8.f * (float)tid + 1.f) - 1.f) * 0.5f);
        while ((l + 1) * (l + 2) / 2 <= tid) ++l;
        while (l * (l + 1) / 2 > tid) --l;
        const int m = tid - l * (l + 1) / 2;
        const int s = l * l + l + m;
        float re = 0.f, im = 0.f;
        #pragma unroll 8
        for (int j = 0; j < 64; ++j) {
            const float2 v = xf[m][j];
            const float w = wig_s2[j * NSPEC + s];
            re += v.x * w; im += v.y * w;
        }
        fhat[(s * BATCH + b) * F_IN + f] = make_float2(re, im);
    }
}

// ---------------- K2: psic[s][o][i] = conj(scaling * sum_g kernel[i,o,g] * Fk[s,g]) ----------------
__global__ __launch_bounds__(256) void k2_psic(const float* __restrict__ kern,
                                               const float* __restrict__ fk_re,
                                               const float* __restrict__ fk_im,
                                               float2* __restrict__ psic) {
    __shared__ float2 fk[NGRID];
    const int s = blockIdx.x;
    const int tid = threadIdx.x;
    if (tid < NGRID) fk[tid] = make_float2(fk_re[s * NGRID + tid], -fk_im[s * NGRID + tid]);
    __syncthreads();
    for (int t = tid; t < F_OUT * F_IN; t += 256) {
        const int o = t >> 4, i = t & 15;
        const float* kr = kern + (size_t)(i * F_OUT + o) * NGRID;
        float re = 0.f, im = 0.f;
        for (int g = 0; g < NGRID; ++g) {
            const float v = kr[g];
            re += v * fk[g].x;
            im += v * fk[g].y;
        }
        psic[(s * F_OUT + o) * F_IN + i] = make_float2(re * SCALING, im * SCALING);
    }
}

// ---------------- K3a: packed half-plane Fz[bo][2856] ----------------
__global__ __launch_bounds__(256) void k3a_fz(const float2* __restrict__ fhat,
                                              const float2* __restrict__ psic,
                                              float2* __restrict__ Fzg) {
    const int bo = blockIdx.x;
    const int b = bo >> 6, o = bo & 63;
    const int tid = threadIdx.x;
    float2* dst = Fzg + (size_t)bo * NHALF;
    #pragma unroll
    for (int l = 0; l < 16; ++l) {
        const int L2 = 2 * l + 1, cnt = (l + 1) * L2;
        for (int t = tid; t < cnt; t += 256) {
            const int m = t / L2;          // const divisor (l unrolled)
            const int nn = t - m * L2;     // n + l
            const float4* fh = (const float4*)(fhat + ((size_t)((l*l + l + m) * BATCH + b) * F_IN));
            const float4* ps = (const float4*)(psic + ((size_t)((l*l + nn) * F_OUT + o) * F_IN));
            float re = 0.f, im = 0.f;
            #pragma unroll
            for (int i = 0; i < 8; ++i) {
                const float4 A = fh[i], C = ps[i];
                re += A.x*C.x - A.y*C.y + A.z*C.z - A.w*C.w;
                im += A.x*C.y + A.y*C.x + A.z*C.w + A.w*C.z;
            }
            dst[d_hof[l] + t] = make_float2(re, im);
        }
    }
}

// ---------------- K3c: per (bo, 4-k chunk): Wigner -> S, column DFT -> G, real row synthesis -> out ----
__global__ __launch_bounds__(256, 4) void k3c_main(const float2* __restrict__ Fzg,
                                                   const float* __restrict__ wig,
                                                   const float* __restrict__ bias,
                                                   float* __restrict__ out) {
    __shared__ float2 S[4][16][33];   // [k][m][n+15], pad 33
    __shared__ float2 G[4][16][33];   // [k][m][g], pad 33
    const int bo = blockIdx.x >> 3;
    const int kc = blockIdx.x & 7;
    const int k0 = kc * 4;
    const int tid = threadIdx.x;
    const float bb = bias[bo & 63];

    const float2* fzb = Fzg + (size_t)bo * NHALF;
    const float* w0 = wig + (size_t)(k0 + 0) * 5456;
    const float* w1 = wig + (size_t)(k0 + 1) * 5456;
    const float* w2 = wig + (size_t)(k0 + 2) * 5456;
    const float* w3 = wig + (size_t)(k0 + 3) * 5456;

    // ----- S-stage: 496 items (m in [0,15], n in [-15,15]) sorted by lam = max(m,|n|) -----
    #pragma unroll
    for (int it = 0; it < 2; ++it) {
        const int t = tid + it * 256;
        if (t < 496) {
            int lam = (int)sqrtf((float)t * 0.5f);
            while ((2*lam + 1) * (lam + 1) <= t) ++lam;
            while (lam > 0 && (2*lam - 1) * lam > t) --lam;
            const int r = t - (2*lam - 1) * lam;
            int m, n;
            if (r < 2*lam + 1) { m = lam; n = r - lam; }
            else { const int r2 = r - (2*lam + 1); m = r2 >> 1; n = (r2 & 1) ? lam : -lam; }
            float sr0=0,si0=0,sr1=0,si1=0,sr2=0,si2=0,sr3=0,si3=0;
            for (int l = lam; l < 16; ++l) {
                const int u = m * (2*l + 1) + n;
                const float2 fz = fzb[d_hof2[l] + u];
                const int wo = d_cof2[l] + u;
                const float wa = w0[wo], wb = w1[wo], wc_ = w2[wo], wd = w3[wo];
                sr0 += fz.x * wa; si0 += fz.y * wa;
                sr1 += fz.x * wb; si1 += fz.y * wb;
                sr2 += fz.x * wc_; si2 += fz.y * wc_;
                sr3 += fz.x * wd; si3 += fz.y * wd;
            }
            const int nn = n + 15;
            S[0][m][nn] = make_float2(sr0, si0);
            S[1][m][nn] = make_float2(sr1, si1);
            S[2][m][nn] = make_float2(sr2, si2);
            S[3][m][nn] = make_float2(sr3, si3);
        }
    }
    __syncthreads();

    // ----- G-phase: G[k][m][g] = sum_n S[k][m][n] e^{i n g w}, 4 g's per thread -----
    {
        const int kk = tid >> 6, m = (tid >> 2) & 15, g0 = tid & 3;
        float wc[4], ws_[4], stc[4], sts[4];
        float ar[4], ai[4], br[4], bi[4];
        #pragma unroll
        for (int q = 0; q < 4; ++q) {
            const float g = (float)(g0 + 4*q);
            sincosf(W32 * g, &sts[q], &stc[q]);           // step e^{i g w}
            sincosf(-15.f * W32 * g, &ws_[q], &wc[q]);    // start e^{-15 i g w}
            ar[q] = ai[q] = br[q] = bi[q] = 0.f;
        }
        const float2* Srow = &S[kk][m][0];
        #pragma unroll
        for (int nn = 0; nn < 31; ++nn) {
            const float2 sv = Srow[nn];
            #pragma unroll
            for (int q = 0; q < 4; ++q) {
                const float X = sv.x * wc[q] - sv.y * ws_[q];
                const float Y = sv.x * ws_[q] + sv.y * wc[q];
                ar[q] += X; ai[q] += Y;
                if ((nn & 1) == 0) { br[q] -= X; bi[q] -= Y; }   // n = nn-15 odd
                else               { br[q] += X; bi[q] += Y; }
            }
            if (nn < 30) {
                #pragma unroll
                for (int q = 0; q < 4; ++q) {
                    const float nc = wc[q]*stc[q] - ws_[q]*sts[q];
                    ws_[q] = wc[q]*sts[q] + ws_[q]*stc[q];
                    wc[q] = nc;
                }
            }
        }
        #pragma unroll
        for (int q = 0; q < 4; ++q) {
            const int g = g0 + 4*q;
            G[kk][m][g]      = make_float2(ar[q], ai[q]);
            G[kk][m][g + 16] = make_float2(br[q], bi[q]);
        }
    }
    __syncthreads();

    // ----- out-phase: out[a,g] = Re G[0,g] + 2 sum_{m=1..15} Re(G[m,g] e^{i m a w}) + bias -----
    {
        const int kk = tid >> 6, g = tid & 31, a0 = (tid >> 5) & 1;
        const float2 g0v = G[kk][0][g];
        const float base = g0v.x + bb;
        float o_[4][4];
        float cA[4], sA[4], pc[4], psn[4];
        #pragma unroll
        for (int rep = 0; rep < 4; ++rep) {
            const int A = a0 + 2 * rep;
            sincosf(W32 * (float)A, &psn[rep], &pc[rep]);
            cA[rep] = 2.f * pc[rep]; sA[rep] = 2.f * psn[rep];  // 2 e^{i A w} (m=1 term)
            #pragma unroll
            for (int j = 0; j < 4; ++j) o_[rep][j] = base;
        }
        #pragma unroll
        for (int m = 1; m < 16; ++m) {
            const float2 gv = G[kk][m][g];
            #pragma unroll
            for (int rep = 0; rep < 4; ++rep) {
                const float X = gv.x * cA[rep] - gv.y * sA[rep];
                const float Y = gv.x * sA[rep] + gv.y * cA[rep];
                o_[rep][0] += X;
                o_[rep][1] += ((m & 3) == 1) ? -Y : ((m & 3) == 2) ? -X : ((m & 3) == 3) ? Y : X;
                o_[rep][2] += (m & 1) ? -X : X;
                o_[rep][3] += ((m & 3) == 1) ? Y : ((m & 3) == 2) ? -X : ((m & 3) == 3) ? -Y : X;
                if (m < 15) {
                    const float nc = cA[rep]*pc[rep] - sA[rep]*psn[rep];
                    sA[rep] = cA[rep]*psn[rep] + sA[rep]*pc[rep];
                    cA[rep] = nc;
                }
            }
        }
        const size_t obase = ((size_t)bo << 15) + ((size_t)(k0 + kk) << 10);
        #pragma unroll
        for (int rep = 0; rep < 4; ++rep) {
            #pragma unroll
            for (int j = 0; j < 4; ++j) {
                const int a = a0 + 2*rep + 8*j;
                out[obase + (a << 5) + g] = o_[rep][j];
            }
        }
    }
}

extern "C" void kernel_launch(void* const* d_in, const int* in_sizes, int n_in,
                              void* d_out, int out_size, void* d_ws, size_t ws_size,
                              hipStream_t stream) {
    const float* x       = (const float*)d_in[0];
    const float* kern    = (const float*)d_in[1];
    const float* bias    = (const float*)d_in[2];
    const float* wig_s2  = (const float*)d_in[3];
    const float* fk_re   = (const float*)d_in[4];
    const float* fk_im   = (const float*)d_in[5];
    const float* wig_so3 = (const float*)d_in[6];
    float* out = (float*)d_out;

    // ws layout: fhat (512 KB) | psic (2 MB) | Fz (23.4 MB)
    float2* fhat = (float2*)d_ws;
    float2* psic = (float2*)((char*)d_ws + (512u << 10));
    float2* Fzg  = (float2*)((char*)d_ws + (512u << 10) + (2u << 20));

    k1_fhat<<<BATCH * F_IN, 256, 0, stream>>>(x, wig_s2, fhat);
    k2_psic<<<NSPEC, 256, 0, stream>>>(kern, fk_re, fk_im, psic);
    k3a_fz<<<BATCH * F_OUT, 256, 0, stream>>>(fhat, psic, Fzg);
    k3c_main<<<BATCH * F_OUT * 8, 256, 0, stream>>>(Fzg, wig_so3, bias, out);
}

// Round 3
// 1061.401 us; speedup vs baseline: 1.1157x; 1.1157x over previous
//
#include <hip/hip_runtime.h>
#include <math.h>

#define BATCH  16
#define F_IN   16
#define F_OUT  64
#define NGRID  32
#define NSPEC  256
#define NU     136           // triangular (l,m>=0) count
#define NITEMS 496           // (m>=0, n) items
#define NP     2856          // packed (item,l) count = sum (l+1)(2l+1)
#define SCALING 0.005524271728019903f
#define PI_F 3.14159265358979323846f
#define W32 0.19634954084936207f   // 2*pi/32

// cof2[l] = c_off[l] + 2l(l+1): wig_so3 offset = cof2[l] + m*(2l+1) + n
__device__ const int d_cof2[16] = {0,5,22,59,124,225,370,567,824,1149,1550,2035,2612,3289,4074,4975};
// cumO[lam]: packed-p start of lam-group; item t in group has run O = cumO + (t-base)*(16-lam)
__device__ const int d_cumO[16] = {0,16,91,217,386,590,821,1071,1332,1596,1855,2101,2326,2522,2681,2795};

// decode packed p -> (l, m, n, lam)
__device__ __forceinline__ void decode_p(int p, int& l, int& m, int& n, int& lam) {
    int L = 0;
    #pragma unroll
    for (int q = 1; q < 16; ++q) if (p >= d_cumO[q]) L = q;
    const int len = 16 - L;
    int q = p - d_cumO[L];
    int ti = (int)((float)q * (1.0f / (float)len));
    int r = q - ti * len;
    if (r < 0) { ti--; r += len; }
    else if (r >= len) { ti++; r -= len; }
    l = L + r;
    lam = L;
    if (ti < 2 * L + 1) { m = L; n = ti - L; }
    else { const int r2 = ti - (2 * L + 1); m = r2 >> 1; n = (r2 & 1) ? L : -L; }
}

// ---------------- K0: wigt[p][k] = wig_so3[k][cof2[l]+m(2l+1)+n] ----------------
__global__ __launch_bounds__(256) void k0_wigt(const float* __restrict__ wig,
                                               float* __restrict__ wigt) {
    const int t = blockIdx.x * 256 + threadIdx.x;
    if (t >= NP * 8) return;
    const int p = t >> 3, kq = t & 7;
    int l, m, n, lam;
    decode_p(p, l, m, n, lam);
    const int wo = d_cof2[l] + m * (2 * l + 1) + n;
    float4 v;
    v.x = wig[(kq * 4 + 0) * 5456 + wo];
    v.y = wig[(kq * 4 + 1) * 5456 + wo];
    v.z = wig[(kq * 4 + 2) * 5456 + wo];
    v.w = wig[(kq * 4 + 3) * 5456 + wo];
    *((float4*)(wigt + p * 32 + kq * 4)) = v;
}

// ---------------- K1: fhat_t[b][u][f], u = triangular (l,m) ----------------
__global__ __launch_bounds__(256) void k1_fhat(const float* __restrict__ x,
                                               const float* __restrict__ wig_s2,
                                               float2* __restrict__ fhat) {
    __shared__ float  xs[64][65];
    __shared__ float2 xf[16][65];
    const int b = blockIdx.x >> 4, f = blockIdx.x & 15;
    const int tid = threadIdx.x;

    const float4* src = (const float4*)(x + (size_t)(b * F_IN + f) * 4096);
    for (int t = tid; t < 1024; t += 256) {
        float4 v = src[t];
        const int row = t >> 4, col = (t & 15) * 4;
        xs[row][col] = v.x; xs[row][col+1] = v.y; xs[row][col+2] = v.z; xs[row][col+3] = v.w;
    }
    __syncthreads();

    {
        const int m = tid >> 4, j0 = tid & 15;
        float stc, sts;
        sincosf(-(2.f * PI_F / 64.f) * (float)m, &sts, &stc);
        float wr = 1.f, wi = 0.f;
        float ar[4] = {0,0,0,0}, ai[4] = {0,0,0,0};
        #pragma unroll 8
        for (int a = 0; a < 64; ++a) {
            #pragma unroll
            for (int q = 0; q < 4; ++q) {
                const float v = xs[j0 + 16*q][a];
                ar[q] += v * wr; ai[q] += v * wi;
            }
            const float nr = wr*stc - wi*sts; wi = wr*sts + wi*stc; wr = nr;
        }
        #pragma unroll
        for (int q = 0; q < 4; ++q) xf[m][j0 + 16*q] = make_float2(ar[q], ai[q]);
    }
    __syncthreads();

    if (tid < NU) {
        int l = (int)((sqrtf(8.f * (float)tid + 1.f) - 1.f) * 0.5f);
        while ((l + 1) * (l + 2) / 2 <= tid) ++l;
        while (l * (l + 1) / 2 > tid) --l;
        const int m = tid - l * (l + 1) / 2;
        const int s = l * l + l + m;
        float re = 0.f, im = 0.f;
        #pragma unroll 8
        for (int j = 0; j < 64; ++j) {
            const float2 v = xf[m][j];
            const float w = wig_s2[j * NSPEC + s];
            re += v.x * w; im += v.y * w;
        }
        fhat[(b * NU + tid) * F_IN + f] = make_float2(re, im);
    }
}

// ---------------- K2: psic_t[o][s][i] = conj(scaling * sum_g kernel[i,o,g]*Fk[s,g]) ----------------
__global__ __launch_bounds__(256) void k2_psic(const float* __restrict__ kern,
                                               const float* __restrict__ fk_re,
                                               const float* __restrict__ fk_im,
                                               float2* __restrict__ psic) {
    __shared__ float2 fk[NGRID];
    const int s = blockIdx.x;
    const int tid = threadIdx.x;
    if (tid < NGRID) fk[tid] = make_float2(fk_re[s * NGRID + tid], -fk_im[s * NGRID + tid]);
    __syncthreads();
    for (int t = tid; t < F_OUT * F_IN; t += 256) {
        const int o = t >> 4, i = t & 15;
        const float* kr = kern + (size_t)(i * F_OUT + o) * NGRID;
        float re = 0.f, im = 0.f;
        for (int g = 0; g < NGRID; ++g) {
            const float v = kr[g];
            re += v * fk[g].x;
            im += v * fk[g].y;
        }
        psic[(o * NSPEC + s) * F_IN + i] = make_float2(re * SCALING, im * SCALING);
    }
}

// ---------------- K3a: fzp[bo][p] packed (item,l), from LDS-staged panels ----------------
__global__ __launch_bounds__(256) void k3a_fz(const float2* __restrict__ fhat,
                                              const float2* __restrict__ psic,
                                              float2* __restrict__ fzp) {
    __shared__ __align__(16) float2 fh[NU][18];
    __shared__ __align__(16) float2 ps[NSPEC][18];
    const int bo = blockIdx.x;
    const int b = bo >> 6, o = bo & 63;
    const int tid = threadIdx.x;

    {
        const float2* src = fhat + (size_t)b * NU * F_IN;
        for (int t = tid; t < NU * F_IN; t += 256) fh[t >> 4][t & 15] = src[t];
        const float2* src2 = psic + (size_t)o * NSPEC * F_IN;
        for (int t = tid; t < NSPEC * F_IN; t += 256) ps[t >> 4][t & 15] = src2[t];
    }
    __syncthreads();

    float2* dst = fzp + (size_t)bo * NP;
    for (int p = tid; p < NP; p += 256) {
        int l, m, n, lam;
        decode_p(p, l, m, n, lam);
        const int u = l * (l + 1) / 2 + m;
        const int sn = l * l + l + n;
        const float4* A4 = (const float4*)&fh[u][0];
        const float4* C4 = (const float4*)&ps[sn][0];
        float re = 0.f, im = 0.f;
        #pragma unroll
        for (int i2 = 0; i2 < 8; ++i2) {
            const float4 A = A4[i2], C = C4[i2];
            re += A.x*C.x - A.y*C.y + A.z*C.z - A.w*C.w;
            im += A.x*C.y + A.y*C.x + A.z*C.w + A.w*C.z;
        }
        dst[p] = make_float2(re, im);
    }
}

// ---------------- K3c: per (bo, 4 k's): S (streamed) -> G -> out (LDS-staged float4) ----------------
__global__ __launch_bounds__(256, 4) void k3c_main(const float2* __restrict__ fzp,
                                                   const float* __restrict__ wigt,
                                                   const float* __restrict__ bias,
                                                   float* __restrict__ out) {
    __shared__ __align__(16) float2 S[4][16][33];   // 16896 B; reused as out staging (16384 B)
    __shared__ __align__(16) float2 G[4][16][33];   // 16896 B
    const int bo = blockIdx.x >> 3;
    const int kc = blockIdx.x & 7;
    const int k0 = kc * 4;
    const int tid = threadIdx.x;
    const float bb = bias[bo & 63];

    const float2* fzb = fzp + (size_t)bo * NP;

    // ----- S-stage: 496 items sorted by lam; contiguous fz run + float4 wigt per l -----
    #pragma unroll
    for (int it = 0; it < 2; ++it) {
        const int t = tid + it * 256;
        if (t < NITEMS) {
            int lam = (int)sqrtf((float)t * 0.5f);
            while ((2*lam + 1) * (lam + 1) <= t) ++lam;
            while (lam > 0 && (2*lam - 1) * lam > t) --lam;
            const int r = t - (2*lam - 1) * lam;
            int m, n;
            if (r < 2*lam + 1) { m = lam; n = r - lam; }
            else { const int r2 = r - (2*lam + 1); m = r2 >> 1; n = (r2 & 1) ? lam : -lam; }
            const int len = 16 - lam;
            const int O = d_cumO[lam] + r * len;
            const float2* fz = fzb + O;
            const float4* wt = (const float4*)(wigt + (size_t)O * 32 + k0);
            float sr0=0,si0=0,sr1=0,si1=0,sr2=0,si2=0,sr3=0,si3=0;
            for (int j = 0; j < len; ++j) {
                const float2 z = fz[j];
                const float4 w = wt[j * 8];
                sr0 += z.x * w.x; si0 += z.y * w.x;
                sr1 += z.x * w.y; si1 += z.y * w.y;
                sr2 += z.x * w.z; si2 += z.y * w.z;
                sr3 += z.x * w.w; si3 += z.y * w.w;
            }
            const int nn = n + 15;
            S[0][m][nn] = make_float2(sr0, si0);
            S[1][m][nn] = make_float2(sr1, si1);
            S[2][m][nn] = make_float2(sr2, si2);
            S[3][m][nn] = make_float2(sr3, si3);
        }
    }
    __syncthreads();

    // ----- G-phase: G[k][m][g] = sum_n S[k][m][n] e^{i n g w} -----
    {
        const int kk = tid >> 6, m = (tid >> 2) & 15, g0 = tid & 3;
        float wc[4], ws_[4], stc[4], sts[4];
        float ar[4], ai[4], br[4], bi[4];
        #pragma unroll
        for (int q = 0; q < 4; ++q) {
            const float g = (float)(g0 + 4*q);
            sincosf(W32 * g, &sts[q], &stc[q]);
            sincosf(-15.f * W32 * g, &ws_[q], &wc[q]);
            ar[q] = ai[q] = br[q] = bi[q] = 0.f;
        }
        const float2* Srow = &S[kk][m][0];
        #pragma unroll
        for (int nn = 0; nn < 31; ++nn) {
            const float2 sv = Srow[nn];
            #pragma unroll
            for (int q = 0; q < 4; ++q) {
                const float X = sv.x * wc[q] - sv.y * ws_[q];
                const float Y = sv.x * ws_[q] + sv.y * wc[q];
                ar[q] += X; ai[q] += Y;
                if ((nn & 1) == 0) { br[q] -= X; bi[q] -= Y; }
                else               { br[q] += X; bi[q] += Y; }
            }
            if (nn < 30) {
                #pragma unroll
                for (int q = 0; q < 4; ++q) {
                    const float nc = wc[q]*stc[q] - ws_[q]*sts[q];
                    ws_[q] = wc[q]*sts[q] + ws_[q]*stc[q];
                    wc[q] = nc;
                }
            }
        }
        #pragma unroll
        for (int q = 0; q < 4; ++q) {
            const int g = g0 + 4*q;
            G[kk][m][g]      = make_float2(ar[q], ai[q]);
            G[kk][m][g + 16] = make_float2(br[q], bi[q]);
        }
    }
    __syncthreads();

    // ----- out-phase: compute into LDS (reusing S), then float4 copy-out -----
    float* outs = (float*)&S[0][0][0];   // 4*32*32 floats = 16384 B
    {
        const int kk = tid >> 6, g = tid & 31, a0 = (tid >> 5) & 1;
        const float2 g0v = G[kk][0][g];
        const float base = g0v.x + bb;
        float o_[4][4];
        float cA[4], sA[4], pc[4], psn[4];
        #pragma unroll
        for (int rep = 0; rep < 4; ++rep) {
            const int A = a0 + 2 * rep;
            sincosf(W32 * (float)A, &psn[rep], &pc[rep]);
            cA[rep] = 2.f * pc[rep]; sA[rep] = 2.f * psn[rep];
            #pragma unroll
            for (int j = 0; j < 4; ++j) o_[rep][j] = base;
        }
        #pragma unroll
        for (int m = 1; m < 16; ++m) {
            const float2 gv = G[kk][m][g];
            #pragma unroll
            for (int rep = 0; rep < 4; ++rep) {
                const float X = gv.x * cA[rep] - gv.y * sA[rep];
                const float Y = gv.x * sA[rep] + gv.y * cA[rep];
                o_[rep][0] += X;
                o_[rep][1] += ((m & 3) == 1) ? -Y : ((m & 3) == 2) ? -X : ((m & 3) == 3) ? Y : X;
                o_[rep][2] += (m & 1) ? -X : X;
                o_[rep][3] += ((m & 3) == 1) ? Y : ((m & 3) == 2) ? -X : ((m & 3) == 3) ? -Y : X;
                if (m < 15) {
                    const float nc = cA[rep]*pc[rep] - sA[rep]*psn[rep];
                    sA[rep] = cA[rep]*psn[rep] + sA[rep]*pc[rep];
                    cA[rep] = nc;
                }
            }
        }
        #pragma unroll
        for (int rep = 0; rep < 4; ++rep) {
            #pragma unroll
            for (int j = 0; j < 4; ++j) {
                const int a = a0 + 2*rep + 8*j;
                outs[kk * 1024 + (a << 5) + g] = o_[rep][j];
            }
        }
    }
    __syncthreads();

    {
        float4* dst = (float4*)(out + (((size_t)bo << 15) + ((size_t)k0 << 10)));
        const float4* s4 = (const float4*)outs;
        #pragma unroll
        for (int it = 0; it < 4; ++it) dst[tid + it * 256] = s4[tid + it * 256];
    }
}

extern "C" void kernel_launch(void* const* d_in, const int* in_sizes, int n_in,
                              void* d_out, int out_size, void* d_ws, size_t ws_size,
                              hipStream_t stream) {
    const float* x       = (const float*)d_in[0];
    const float* kern    = (const float*)d_in[1];
    const float* bias    = (const float*)d_in[2];
    const float* wig_s2  = (const float*)d_in[3];
    const float* fk_re   = (const float*)d_in[4];
    const float* fk_im   = (const float*)d_in[5];
    const float* wig_so3 = (const float*)d_in[6];
    float* out = (float*)d_out;

    // ws layout
    float2* fhat_t = (float2*)d_ws;                                   // 16*136*16*8   = 278528
    float2* psic_t = (float2*)((char*)d_ws + 327680);                 // 64*256*16*8   = 2097152
    float*  wigt   = (float*)((char*)d_ws + 2424832);                 // 2856*32*4     = 365568
    float2* fzp    = (float2*)((char*)d_ws + 2790400);                // 1024*2856*8   = 23396352

    k0_wigt<<<(NP * 8 + 255) / 256, 256, 0, stream>>>(wig_so3, wigt);
    k1_fhat<<<BATCH * F_IN, 256, 0, stream>>>(x, wig_s2, fhat_t);
    k2_psic<<<NSPEC, 256, 0, stream>>>(kern, fk_re, fk_im, psic_t);
    k3a_fz<<<BATCH * F_OUT, 256, 0, stream>>>(fhat_t, psic_t, fzp);
    k3c_main<<<BATCH * F_OUT * 8, 256, 0, stream>>>(fzp, wigt, bias, out);
}

// Round 4
// 352.596 us; speedup vs baseline: 3.3585x; 3.0102x over previous
//
#include <hip/hip_runtime.h>
#include <math.h>

#define BATCH  16
#define F_IN   16
#define F_OUT  64
#define NGRID  32
#define NSPEC  256
#define NU     136           // triangular (l,m>=0) count
#define NITEMS 496           // (m>=0, n) items
#define NP     2856          // packed (item,l) count = sum (l+1)(2l+1)
#define SCALING 0.005524271728019903f
#define PI_F 3.14159265358979323846f
#define W32 0.19634954084936207f   // 2*pi/32

// cof2[l] = c_off[l] + 2l(l+1): wig_so3 offset = cof2[l] + m*(2l+1) + n
__device__ const int d_cof2[16] = {0,5,22,59,124,225,370,567,824,1149,1550,2035,2612,3289,4074,4975};
// cumO[lam]: packed-p start of lam-group; item t in group has run O = cumO + (t-base)*(16-lam)
__device__ const int d_cumO[16] = {0,16,91,217,386,590,821,1071,1332,1596,1855,2101,2326,2522,2681,2795};

// decode packed p -> (l, m, n, lam)
__device__ __forceinline__ void decode_p(int p, int& l, int& m, int& n, int& lam) {
    int L = 0;
    #pragma unroll
    for (int q = 1; q < 16; ++q) if (p >= d_cumO[q]) L = q;
    const int len = 16 - L;
    int q = p - d_cumO[L];
    int ti = (int)((float)q * (1.0f / (float)len));
    int r = q - ti * len;
    if (r < 0) { ti--; r += len; }
    else if (r >= len) { ti++; r -= len; }
    l = L + r;
    lam = L;
    if (ti < 2 * L + 1) { m = L; n = ti - L; }
    else { const int r2 = ti - (2 * L + 1); m = r2 >> 1; n = (r2 & 1) ? L : -L; }
}

// ---------------- K0: wigt[kc][p][c] = wig_so3[kc*4+c][cof2[l]+m(2l+1)+n] ----------------
__global__ __launch_bounds__(256) void k0_wigt(const float* __restrict__ wig,
                                               float* __restrict__ wigt) {
    const int t = blockIdx.x * 256 + threadIdx.x;
    if (t >= NP * 8) return;
    const int p = t >> 3, kq = t & 7;
    int l, m, n, lam;
    decode_p(p, l, m, n, lam);
    const int wo = d_cof2[l] + m * (2 * l + 1) + n;
    float4 v;
    v.x = wig[(kq * 4 + 0) * 5456 + wo];
    v.y = wig[(kq * 4 + 1) * 5456 + wo];
    v.z = wig[(kq * 4 + 2) * 5456 + wo];
    v.w = wig[(kq * 4 + 3) * 5456 + wo];
    *((float4*)(wigt + ((size_t)kq * NP + p) * 4)) = v;
}

// ---------------- K1: fhat_t[b][u][f], u = triangular (l,m) ----------------
__global__ __launch_bounds__(256) void k1_fhat(const float* __restrict__ x,
                                               const float* __restrict__ wig_s2,
                                               float2* __restrict__ fhat) {
    __shared__ float  xs[64][65];
    __shared__ float2 xf[16][65];
    const int b = blockIdx.x >> 4, f = blockIdx.x & 15;
    const int tid = threadIdx.x;

    const float4* src = (const float4*)(x + (size_t)(b * F_IN + f) * 4096);
    for (int t = tid; t < 1024; t += 256) {
        float4 v = src[t];
        const int row = t >> 4, col = (t & 15) * 4;
        xs[row][col] = v.x; xs[row][col+1] = v.y; xs[row][col+2] = v.z; xs[row][col+3] = v.w;
    }
    __syncthreads();

    {
        const int m = tid >> 4, j0 = tid & 15;
        float stc, sts;
        sincosf(-(2.f * PI_F / 64.f) * (float)m, &sts, &stc);
        float wr = 1.f, wi = 0.f;
        float ar[4] = {0,0,0,0}, ai[4] = {0,0,0,0};
        #pragma unroll 8
        for (int a = 0; a < 64; ++a) {
            #pragma unroll
            for (int q = 0; q < 4; ++q) {
                const float v = xs[j0 + 16*q][a];
                ar[q] += v * wr; ai[q] += v * wi;
            }
            const float nr = wr*stc - wi*sts; wi = wr*sts + wi*stc; wr = nr;
        }
        #pragma unroll
        for (int q = 0; q < 4; ++q) xf[m][j0 + 16*q] = make_float2(ar[q], ai[q]);
    }
    __syncthreads();

    if (tid < NU) {
        int l = (int)((sqrtf(8.f * (float)tid + 1.f) - 1.f) * 0.5f);
        while ((l + 1) * (l + 2) / 2 <= tid) ++l;
        while (l * (l + 1) / 2 > tid) --l;
        const int m = tid - l * (l + 1) / 2;
        const int s = l * l + l + m;
        float re = 0.f, im = 0.f;
        #pragma unroll 8
        for (int j = 0; j < 64; ++j) {
            const float2 v = xf[m][j];
            const float w = wig_s2[j * NSPEC + s];
            re += v.x * w; im += v.y * w;
        }
        fhat[(b * NU + tid) * F_IN + f] = make_float2(re, im);
    }
}

// ---------------- K2: psic_t[o][s][i] = conj(scaling * sum_g kernel[i,o,g]*Fk[s,g]) ----------------
__global__ __launch_bounds__(256) void k2_psic(const float* __restrict__ kern,
                                               const float* __restrict__ fk_re,
                                               const float* __restrict__ fk_im,
                                               float2* __restrict__ psic) {
    __shared__ float2 fk[NGRID];
    const int s = blockIdx.x;
    const int tid = threadIdx.x;
    if (tid < NGRID) fk[tid] = make_float2(fk_re[s * NGRID + tid], -fk_im[s * NGRID + tid]);
    __syncthreads();
    for (int t = tid; t < F_OUT * F_IN; t += 256) {
        const int o = t >> 4, i = t & 15;
        const float* kr = kern + (size_t)(i * F_OUT + o) * NGRID;
        float re = 0.f, im = 0.f;
        for (int g = 0; g < NGRID; ++g) {
            const float v = kr[g];
            re += v * fk[g].x;
            im += v * fk[g].y;
        }
        psic[(o * NSPEC + s) * F_IN + i] = make_float2(re * SCALING, im * SCALING);
    }
}

// ---------------- K3a: fzp[bo][p] packed (item,l), from LDS-staged panels ----------------
__global__ __launch_bounds__(256) void k3a_fz(const float2* __restrict__ fhat,
                                              const float2* __restrict__ psic,
                                              float2* __restrict__ fzp) {
    __shared__ __align__(16) float2 fh[NU][18];
    __shared__ __align__(16) float2 ps[NSPEC][18];
    const int bo = blockIdx.x;
    const int b = bo >> 6, o = bo & 63;
    const int tid = threadIdx.x;

    {
        const float2* src = fhat + (size_t)b * NU * F_IN;
        for (int t = tid; t < NU * F_IN; t += 256) fh[t >> 4][t & 15] = src[t];
        const float2* src2 = psic + (size_t)o * NSPEC * F_IN;
        for (int t = tid; t < NSPEC * F_IN; t += 256) ps[t >> 4][t & 15] = src2[t];
    }
    __syncthreads();

    float2* dst = fzp + (size_t)bo * NP;
    for (int p = tid; p < NP; p += 256) {
        int l, m, n, lam;
        decode_p(p, l, m, n, lam);
        const int u = l * (l + 1) / 2 + m;
        const int sn = l * l + l + n;
        const float4* A4 = (const float4*)&fh[u][0];
        const float4* C4 = (const float4*)&ps[sn][0];
        float re = 0.f, im = 0.f;
        #pragma unroll
        for (int i2 = 0; i2 < 8; ++i2) {
            const float4 A = A4[i2], C = C4[i2];
            re += A.x*C.x - A.y*C.y + A.z*C.z - A.w*C.w;
            im += A.x*C.y + A.y*C.x + A.z*C.w + A.w*C.z;
        }
        dst[p] = make_float2(re, im);
    }
}

// ---------------- K3c: per (bo, 4 k's): S (streamed) -> G -> out; tw table, no recurrences ----
__global__ __launch_bounds__(256) void k3c_main(const float2* __restrict__ fzp,
                                               const float* __restrict__ wigt,
                                               const float* __restrict__ bias,
                                               float* __restrict__ out) {
    __shared__ __align__(16) float2 S[4][16][33];   // 16896 B; reused as out staging
    __shared__ __align__(16) float2 G[4][16][33];   // 16896 B
    __shared__ float2 tw[32];                       // e^{+i q w}
    const int bo = blockIdx.x >> 3;
    const int kc = blockIdx.x & 7;
    const int tid = threadIdx.x;
    const float bb = bias[bo & 63];

    if (tid < 32) {
        float s_, c_;
        sincosf(W32 * (float)tid, &s_, &c_);
        tw[tid] = make_float2(c_, s_);
    }

    const float2* fzb = fzp + (size_t)bo * NP;
    const float4* wtb = (const float4*)wigt + (size_t)kc * NP;

    // ----- S-stage: 496 items sorted by lam; contiguous fz float2 + contiguous wigt float4 -----
    #pragma unroll
    for (int it = 0; it < 2; ++it) {
        const int t = tid + it * 256;
        if (t < NITEMS) {
            int lam = (int)sqrtf((float)t * 0.5f);
            while ((2*lam + 1) * (lam + 1) <= t) ++lam;
            while (lam > 0 && (2*lam - 1) * lam > t) --lam;
            const int r = t - (2*lam - 1) * lam;
            int m, n;
            if (r < 2*lam + 1) { m = lam; n = r - lam; }
            else { const int r2 = r - (2*lam + 1); m = r2 >> 1; n = (r2 & 1) ? lam : -lam; }
            const int len = 16 - lam;
            const int O = d_cumO[lam] + r * len;
            const float2* fz = fzb + O;
            const float4* wt = wtb + O;
            float sr0=0,si0=0,sr1=0,si1=0,sr2=0,si2=0,sr3=0,si3=0;
            for (int j = 0; j < len; ++j) {
                const float2 z = fz[j];
                const float4 w = wt[j];
                sr0 += z.x * w.x; si0 += z.y * w.x;
                sr1 += z.x * w.y; si1 += z.y * w.y;
                sr2 += z.x * w.z; si2 += z.y * w.z;
                sr3 += z.x * w.w; si3 += z.y * w.w;
            }
            const int nn = n + 15;
            S[0][m][nn] = make_float2(sr0, si0);
            S[1][m][nn] = make_float2(sr1, si1);
            S[2][m][nn] = make_float2(sr2, si2);
            S[3][m][nn] = make_float2(sr3, si3);
        }
    }
    __syncthreads();

    // ----- G-phase: G[k][m][g] = sum_n S[k][m][n] e^{i n g w}; tw-table lookups -----
    {
        const int kk = tid >> 6, m = (tid >> 2) & 15, g0 = tid & 3;
        float ar[4] = {0,0,0,0}, ai[4] = {0,0,0,0}, br[4] = {0,0,0,0}, bi[4] = {0,0,0,0};
        const float2* Srow = &S[kk][m][0];
        #pragma unroll
        for (int nn = 0; nn < 31; ++nn) {
            const float2 sv = Srow[nn];
            const int n = nn - 15;
            #pragma unroll
            for (int q = 0; q < 4; ++q) {
                const int g = g0 + 4 * q;
                const float2 w = tw[(n * g) & 31];
                const float X = sv.x * w.x - sv.y * w.y;
                const float Y = sv.x * w.y + sv.y * w.x;
                ar[q] += X; ai[q] += Y;
                if (nn & 1) { br[q] += X; bi[q] += Y; }   // n even
                else        { br[q] -= X; bi[q] -= Y; }   // n odd: e^{i n pi} = -1
            }
        }
        #pragma unroll
        for (int q = 0; q < 4; ++q) {
            const int g = g0 + 4 * q;
            G[kk][m][g]      = make_float2(ar[q], ai[q]);
            G[kk][m][g + 16] = make_float2(br[q], bi[q]);
        }
    }
    __syncthreads();

    // ----- out-phase: out[a,g] = ReG[0,g] + 2 sum_m Re(G[m,g] e^{i m a w}) + bias; tw table -----
    float* outs = (float*)&S[0][0][0];   // 4*32*32 floats = 16384 B
    {
        const int kk = tid >> 6, g = tid & 31, a0 = (tid >> 5) & 1;
        const float base = G[kk][0][g].x + bb;
        float o_[4][4];
        #pragma unroll
        for (int rep = 0; rep < 4; ++rep)
            #pragma unroll
            for (int j = 0; j < 4; ++j) o_[rep][j] = base;
        #pragma unroll
        for (int m = 1; m < 16; ++m) {
            const float2 gv = G[kk][m][g];
            const float gx = 2.f * gv.x, gy = 2.f * gv.y;
            #pragma unroll
            for (int rep = 0; rep < 4; ++rep) {
                const int A = a0 + 2 * rep;
                const float2 w = tw[(m * A) & 31];
                const float X = gx * w.x - gy * w.y;
                const float Y = gx * w.y + gy * w.x;
                o_[rep][0] += X;
                o_[rep][1] += ((m & 3) == 1) ? -Y : ((m & 3) == 2) ? -X : ((m & 3) == 3) ? Y : X;
                o_[rep][2] += (m & 1) ? -X : X;
                o_[rep][3] += ((m & 3) == 1) ? Y : ((m & 3) == 2) ? -X : ((m & 3) == 3) ? -Y : X;
            }
        }
        #pragma unroll
        for (int rep = 0; rep < 4; ++rep) {
            #pragma unroll
            for (int j = 0; j < 4; ++j) {
                const int a = a0 + 2*rep + 8*j;
                outs[kk * 1024 + (a << 5) + g] = o_[rep][j];
            }
        }
    }
    __syncthreads();

    {
        const int k0 = kc * 4;
        float4* dst = (float4*)(out + (((size_t)bo << 15) + ((size_t)k0 << 10)));
        const float4* s4 = (const float4*)outs;
        #pragma unroll
        for (int it = 0; it < 4; ++it) dst[tid + it * 256] = s4[tid + it * 256];
    }
}

extern "C" void kernel_launch(void* const* d_in, const int* in_sizes, int n_in,
                              void* d_out, int out_size, void* d_ws, size_t ws_size,
                              hipStream_t stream) {
    const float* x       = (const float*)d_in[0];
    const float* kern    = (const float*)d_in[1];
    const float* bias    = (const float*)d_in[2];
    const float* wig_s2  = (const float*)d_in[3];
    const float* fk_re   = (const float*)d_in[4];
    const float* fk_im   = (const float*)d_in[5];
    const float* wig_so3 = (const float*)d_in[6];
    float* out = (float*)d_out;

    // ws layout
    float2* fhat_t = (float2*)d_ws;                                   // 16*136*16*8   = 278528
    float2* psic_t = (float2*)((char*)d_ws + 327680);                 // 64*256*16*8   = 2097152
    float*  wigt   = (float*)((char*)d_ws + 2424832);                 // 8*2856*4*4    = 365568
    float2* fzp    = (float2*)((char*)d_ws + 2790400);                // 1024*2856*8   = 23396352

    k0_wigt<<<(NP * 8 + 255) / 256, 256, 0, stream>>>(wig_so3, wigt);
    k1_fhat<<<BATCH * F_IN, 256, 0, stream>>>(x, wig_s2, fhat_t);
    k2_psic<<<NSPEC, 256, 0, stream>>>(kern, fk_re, fk_im, psic_t);
    k3a_fz<<<BATCH * F_OUT, 256, 0, stream>>>(fhat_t, psic_t, fzp);
    k3c_main<<<BATCH * F_OUT * 8, 256, 0, stream>>>(fzp, wigt, bias, out);
}